// Round 3
// baseline (156.147 us; speedup 1.0000x reference)
//
#include <hip/hip_runtime.h>
#include <math.h>

#define BATCH 2
#define SEQ 2048
#define DMODEL 512
#define NH 8
#define HDIM 64
#define MTOT (BATCH * SEQ)              // 4096
#define QSIZE (BATCH * NH * SEQ * HDIM) // 2097152 elems per tensor
#define WSIZE (DMODEL * DMODEL)         // 262144 elems per weight

typedef __attribute__((ext_vector_type(8))) short bf16x8;
typedef __attribute__((ext_vector_type(4))) float f32x4;

__device__ inline unsigned short f2bf(float f) {
    union { float f; unsigned u; } v; v.f = f;
    unsigned u = v.u;
    u += 0x7fffu + ((u >> 16) & 1u);
    return (unsigned short)(u >> 16);
}
// hardware packed f32->bf16 (RTNE), 1 instr
__device__ inline unsigned pack2(float lo, float hi) {
    unsigned r;
    asm("v_cvt_pk_bf16_f32 %0, %1, %2" : "=v"(r) : "v"(lo), "v"(hi));
    return r;
}

// LDS row stride: 72 elems = 144 B (16B-aligned for ds_read_b128).
#define LSTR 72

// ws layout (bf16 elems):
#define WS_Q   ((size_t)0)
#define WS_K   ((size_t)QSIZE)
#define WS_V   (2 * (size_t)QSIZE)        // [B,H,HD,S] transposed
#define WS_CTX (3 * (size_t)QSIZE)
#define WS_WT  (4 * (size_t)QSIZE)        // 4 transposed weights

// Q pre-scale: 1/sqrt(64) * log2(e)  (attn uses exp2 directly)
#define QSCALE 0.1803368801111204f

// ---------------------------------------------------------------------------
// Kernel 0: transpose + bf16-convert the 4 weight matrices.
// ---------------------------------------------------------------------------
__global__ __launch_bounds__(256) void wt_prep_kernel(
    const float* __restrict__ Wq, const float* __restrict__ Wk,
    const float* __restrict__ Wv, const float* __restrict__ Wo,
    unsigned short* __restrict__ wt)
{
    const int z = blockIdx.z;
    const float* W = (z == 0) ? Wq : (z == 1) ? Wk : (z == 2) ? Wv : Wo;
    unsigned short* Wt = wt + (size_t)z * WSIZE;

    __shared__ float T[32][33];
    const int tid = threadIdx.x;
    const int k0 = blockIdx.x * 32, n0 = blockIdx.y * 32;

    {
        int r = tid >> 3, c = (tid & 7) * 4;
        float4 v = *(const float4*)&W[(size_t)(k0 + r) * DMODEL + n0 + c];
        T[r][c + 0] = v.x; T[r][c + 1] = v.y; T[r][c + 2] = v.z; T[r][c + 3] = v.w;
    }
    __syncthreads();
    {
        int n = tid >> 3, c = (tid & 7) * 4;
        uint2 o;
        o.x = pack2(T[c + 0][n], T[c + 1][n]);
        o.y = pack2(T[c + 2][n], T[c + 3][n]);
        *(uint2*)&Wt[(size_t)(n0 + n) * DMODEL + k0 + c] = o;
    }
}

// ---------------------------------------------------------------------------
// Kernel 1: fused QKV projection. fp32 inputs read DIRECTLY (no prep kernel,
// no A-LDS: each wave owns disjoint A rows, loads per-lane fp32 + cvt_pk).
// B (transposed weight) double-buffered in LDS, 1 barrier per K-step.
// Q scaled by QSCALE (=0.125*log2e). Q,K stored [B,H,S,HD]; V stored [B,H,HD,S].
// ---------------------------------------------------------------------------
__global__ __launch_bounds__(256) void qkv_mfma_kernel(
    unsigned short* __restrict__ ws,
    const float* __restrict__ qin, const float* __restrict__ kin,
    const float* __restrict__ vin,
    const float* __restrict__ bq, const float* __restrict__ bk,
    const float* __restrict__ bv)
{
    const int which = blockIdx.z;
    const float* A = (which == 0) ? qin : (which == 1) ? kin : vin;
    const unsigned short* Wt = ws + WS_WT + (size_t)which * WSIZE;
    const float* bias = (which == 0) ? bq : (which == 1) ? bk : bv;
    unsigned short* out = ws + (size_t)which * QSIZE;

    __shared__ __align__(16) short Bs[2][128][LSTR];

    const int tid = threadIdx.x;
    const int lane = tid & 63, wave = tid >> 6;
    const int lrow = lane & 15, quad = lane >> 4;
    const int m0 = blockIdx.y * 128, n0 = blockIdx.x * 128;

    const int sr = tid >> 1, sh = (tid & 1) * 32;
    const unsigned short* wp0 = Wt + (size_t)(n0 + sr) * DMODEL + sh;

    const float* arow0 = A + (size_t)(m0 + wave * 32 + lrow) * DMODEL;
    const float* arow1 = arow0 + 16 * DMODEL;

    f32x4 acc[2][8];
    #pragma unroll
    for (int i = 0; i < 2; ++i)
        #pragma unroll
        for (int n = 0; n < 8; ++n) acc[i][n] = f32x4{0.f, 0.f, 0.f, 0.f};

    uint4 b0, b1, b2, b3;
#define LOADB(K0) do { const unsigned short* wp = wp0 + (K0); \
        b0 = *(const uint4*)(wp + 0);  b1 = *(const uint4*)(wp + 8); \
        b2 = *(const uint4*)(wp + 16); b3 = *(const uint4*)(wp + 24); } while (0)
#define WRITEB(BUF) do { \
        *(uint4*)&Bs[BUF][sr][sh + 0]  = b0; *(uint4*)&Bs[BUF][sr][sh + 8]  = b1; \
        *(uint4*)&Bs[BUF][sr][sh + 16] = b2; *(uint4*)&Bs[BUF][sr][sh + 24] = b3; } while (0)

    LOADB(0);
    WRITEB(0);
    LOADB(64);

    #pragma unroll
    for (int kk = 0; kk < 8; ++kk) {
        const int k0 = kk * 64, cur = kk & 1;
        __syncthreads();   // Bs[cur] ready; Bs[cur^1] free
        __builtin_amdgcn_s_setprio(1);
        #pragma unroll
        for (int s = 0; s < 2; ++s) {
            const int cb = k0 + s * 32 + quad * 8;
            bf16x8 af[2];
            {
                float4 f0 = *(const float4*)(arow0 + cb);
                float4 f1 = *(const float4*)(arow0 + cb + 4);
                union { unsigned w[4]; bf16x8 v; } U;
                U.w[0] = pack2(f0.x, f0.y); U.w[1] = pack2(f0.z, f0.w);
                U.w[2] = pack2(f1.x, f1.y); U.w[3] = pack2(f1.z, f1.w);
                af[0] = U.v;
            }
            {
                float4 f0 = *(const float4*)(arow1 + cb);
                float4 f1 = *(const float4*)(arow1 + cb + 4);
                union { unsigned w[4]; bf16x8 v; } U;
                U.w[0] = pack2(f0.x, f0.y); U.w[1] = pack2(f0.z, f0.w);
                U.w[2] = pack2(f1.x, f1.y); U.w[3] = pack2(f1.z, f1.w);
                af[1] = U.v;
            }
            #pragma unroll
            for (int n = 0; n < 8; ++n) {
                bf16x8 bfv = *(const bf16x8*)&Bs[cur][n * 16 + lrow][s * 32 + quad * 8];
                acc[0][n] = __builtin_amdgcn_mfma_f32_16x16x32_bf16(af[0], bfv, acc[0][n], 0, 0, 0);
                acc[1][n] = __builtin_amdgcn_mfma_f32_16x16x32_bf16(af[1], bfv, acc[1][n], 0, 0, 0);
            }
        }
        __builtin_amdgcn_s_setprio(0);
        if (kk < 7) WRITEB(cur ^ 1);   // regs hold step kk+1
        if (kk < 6) LOADB(k0 + 128);   // issue step kk+2
    }
#undef LOADB
#undef WRITEB

    if (which < 2) {
        const float scale = (which == 0) ? QSCALE : 1.0f;
        #pragma unroll
        for (int n = 0; n < 8; ++n) {
            const int col = n0 + n * 16 + lrow;
            const int h_ = col >> 6, hd_ = col & 63;
            const float bv_ = bias[col];
            #pragma unroll
            for (int i = 0; i < 2; ++i) {
                #pragma unroll
                for (int r = 0; r < 4; ++r) {
                    const int m = m0 + wave * 32 + i * 16 + quad * 4 + r;
                    const int b_ = m >> 11, s_ = m & (SEQ - 1);
                    const float v = (acc[i][n][r] + bv_) * scale;
                    out[((size_t)((b_ * NH + h_) * SEQ + s_)) * HDIM + hd_] = f2bf(v);
                }
            }
        }
    } else {
        #pragma unroll
        for (int n = 0; n < 8; ++n) {
            const int col = n0 + n * 16 + lrow;
            const int h_ = col >> 6, hd_ = col & 63;
            const float bv_ = bias[col];
            #pragma unroll
            for (int i = 0; i < 2; ++i) {
                const int m = m0 + wave * 32 + i * 16 + quad * 4;
                const int b_ = m >> 11, s_ = m & (SEQ - 1);
                uint2 o;
                o.x = pack2(acc[i][n][0] + bv_, acc[i][n][1] + bv_);
                o.y = pack2(acc[i][n][2] + bv_, acc[i][n][3] + bv_);
                *(uint2*)&out[((size_t)((b_ * NH + h_) * HDIM + hd_)) * SEQ + s_] = o;
            }
        }
    }
}

// ---------------------------------------------------------------------------
// Kernel 2: bf16 MFMA flash attention (S^T form, key-split halves,
// double-buffered K/V, zero-shuffle P via tau-permuted Vt columns,
// XCD swizzle). This round: exp2 path (Q carries log2e), tree max
// (max3-fusable), cross-lane l-reduction deferred out of the loop.
// grid = (16, 32) swizzled, 512 thr.
// ---------------------------------------------------------------------------
#define HSEQ (SEQ / 2)   // 1024 keys per half
#define NT   (HSEQ / 64) // 16 tiles per half
#define OSTR 68          // merge O buffer row stride (floats), bank-spread
#define THR2 11.0f       // defer-max threshold in log2 units (~e^7.6)

__global__ __launch_bounds__(512) void attn_mfma_kernel(
    const unsigned short* __restrict__ ws, unsigned short* __restrict__ ctx)
{
    const unsigned short* Q = ws + WS_Q;   // pre-scaled by 0.125*log2e
    const unsigned short* K = ws + WS_K;
    const unsigned short* V = ws + WS_V;   // [B,H,HD,S]

    __shared__ __align__(16) short Ks[2][2][64][LSTR];  // [half][buf][key][hd]
    __shared__ __align__(16) short Vt[2][2][64][LSTR];  // [half][buf][hd][perm key]

    // XCD-aware swizzle: bid mod 8 == bh mod 8.
    const int lin = blockIdx.x + 16 * blockIdx.y;          // 0..511
    const int bh  = (lin & 7) + 8 * (lin >> 8);
    const int q0  = ((lin >> 3) & 31) * 64;

    const int tid = threadIdx.x;
    const int lane = tid & 63, wave = tid >> 6;
    const int half = wave >> 2, w4 = wave & 3;
    const int lrow = lane & 15, quad = lane >> 4;
    const size_t base = (size_t)bh * SEQ * HDIM;

    const unsigned short* qrow = Q + base + (size_t)(q0 + w4 * 16 + lrow) * HDIM;
    const bf16x8 qb0 = *(const bf16x8*)(qrow + quad * 8);
    const bf16x8 qb1 = *(const bf16x8*)(qrow + 32 + quad * 8);

    float m_prev = -1e30f, l_run = 0.f;   // m in log2 units; l per-lane partial
    f32x4 oacc[4];
    #pragma unroll
    for (int n = 0; n < 4; ++n) oacc[n] = f32x4{0.f, 0.f, 0.f, 0.f};

    const int t  = tid & 255;
    const int kr = t >> 2;
    const int kc = (t & 3) * 16;
    const int n_ = t & 3;
    const int c0 = ((n_ >= 2) ? 32 : 0) + (n_ & 1) * 4;  // tau col base
    const int ktbase = half * HSEQ;

    const unsigned short* kptr = K + base + (size_t)(ktbase + kr) * HDIM + kc;
    const unsigned short* vptr = V + base + (size_t)kr * SEQ + ktbase + kc;

    uint4 kA, kB, vA, vB;
#define LOADT(TI) do { \
        const unsigned short* kp = kptr + (size_t)(TI) * 64 * HDIM; \
        const unsigned short* vp = vptr + (TI) * 64; \
        kA = *(const uint4*)kp; kB = *(const uint4*)(kp + 8); \
        vA = *(const uint4*)vp; vB = *(const uint4*)(vp + 8); \
    } while (0)
#define WRITET(BUF) do { \
        *(uint4*)&Ks[half][BUF][kr][kc]     = kA; \
        *(uint4*)&Ks[half][BUF][kr][kc + 8] = kB; \
        uint2 w0; w0.x = vA.x; w0.y = vA.y; \
        uint2 w1; w1.x = vA.z; w1.y = vA.w; \
        uint2 w2; w2.x = vB.x; w2.y = vB.y; \
        uint2 w3; w3.x = vB.z; w3.y = vB.w; \
        *(uint2*)&Vt[half][BUF][kr][c0]      = w0; \
        *(uint2*)&Vt[half][BUF][kr][c0 + 8]  = w1; \
        *(uint2*)&Vt[half][BUF][kr][c0 + 16] = w2; \
        *(uint2*)&Vt[half][BUF][kr][c0 + 24] = w3; \
    } while (0)

    LOADT(0);
    WRITET(0);
    LOADT(1);

    #pragma unroll 2
    for (int ti = 0; ti < NT; ++ti) {
        const int cur = ti & 1;
        __syncthreads();

        // ---- S^T = K·Q^T ----
        f32x4 st[4];
        __builtin_amdgcn_s_setprio(1);
        #pragma unroll
        for (int n = 0; n < 4; ++n) {
            bf16x8 ka0 = *(const bf16x8*)&Ks[half][cur][n * 16 + lrow][quad * 8];
            bf16x8 ka1 = *(const bf16x8*)&Ks[half][cur][n * 16 + lrow][32 + quad * 8];
            f32x4 z = f32x4{0.f, 0.f, 0.f, 0.f};
            z = __builtin_amdgcn_mfma_f32_16x16x32_bf16(ka0, qb0, z, 0, 0, 0);
            z = __builtin_amdgcn_mfma_f32_16x16x32_bf16(ka1, qb1, z, 0, 0, 0);
            st[n] = z;
        }
        __builtin_amdgcn_s_setprio(0);

        // ---- max: tree (max3-fusable), then cross-quad shfl ----
        float t0 = fmaxf(fmaxf(st[0][0], st[0][1]), fmaxf(st[0][2], st[0][3]));
        float t1 = fmaxf(fmaxf(st[1][0], st[1][1]), fmaxf(st[1][2], st[1][3]));
        float t2 = fmaxf(fmaxf(st[2][0], st[2][1]), fmaxf(st[2][2], st[2][3]));
        float t3 = fmaxf(fmaxf(st[3][0], st[3][1]), fmaxf(st[3][2], st[3][3]));
        float tmax = fmaxf(fmaxf(t0, t1), fmaxf(t2, t3));
        tmax = fmaxf(tmax, __shfl_xor(tmax, 16));
        tmax = fmaxf(tmax, __shfl_xor(tmax, 32));

        // defer-max (T13): rescale only when max grows past THR2 (log2 units)
        if (!__all(tmax <= m_prev + THR2)) {
            const float mnew = fmaxf(m_prev, tmax);
            const float alpha = exp2f(m_prev - mnew);
            l_run *= alpha;
            #pragma unroll
            for (int n = 0; n < 4; ++n) {
                oacc[n][0] *= alpha; oacc[n][1] *= alpha;
                oacc[n][2] *= alpha; oacc[n][3] *= alpha;
            }
            m_prev = mnew;
        }

        float p[4][4];
        float tsum = 0.f;
        #pragma unroll
        for (int n = 0; n < 4; ++n)
            #pragma unroll
            for (int r = 0; r < 4; ++r) {
                p[n][r] = exp2f(st[n][r] - m_prev);
                tsum += p[n][r];
            }
        l_run += tsum;   // per-lane partial; cross-lane reduce deferred to end

        // ---- P -> PV B-fragments, in-register (zero-shuffle via tau) ----
        union { unsigned w[4]; bf16x8 v; } U0, U1;
        U0.w[0] = pack2(p[0][0], p[0][1]); U0.w[1] = pack2(p[0][2], p[0][3]);
        U0.w[2] = pack2(p[1][0], p[1][1]); U0.w[3] = pack2(p[1][2], p[1][3]);
        U1.w[0] = pack2(p[2][0], p[2][1]); U1.w[1] = pack2(p[2][2], p[2][3]);
        U1.w[2] = pack2(p[3][0], p[3][1]); U1.w[3] = pack2(p[3][2], p[3][3]);

        // ---- O^T += V^T·P^T ----
        __builtin_amdgcn_s_setprio(1);
        #pragma unroll
        for (int n = 0; n < 4; ++n) {
            bf16x8 va0 = *(const bf16x8*)&Vt[half][cur][n * 16 + lrow][quad * 8];
            bf16x8 va1 = *(const bf16x8*)&Vt[half][cur][n * 16 + lrow][32 + quad * 8];
            oacc[n] = __builtin_amdgcn_mfma_f32_16x16x32_bf16(va0, U0.v, oacc[n], 0, 0, 0);
            oacc[n] = __builtin_amdgcn_mfma_f32_16x16x32_bf16(va1, U1.v, oacc[n], 0, 0, 0);
        }
        __builtin_amdgcn_s_setprio(0);

        if (ti < NT - 1) WRITET(cur ^ 1);
        if (ti < NT - 2) LOADT(ti + 2);
    }
#undef LOADT
#undef WRITET

    // deferred l reduction: make l uniform across the 4 lanes sharing a q
    l_run += __shfl_xor(l_run, 16);
    l_run += __shfl_xor(l_run, 32);

    // ---- merge halves through LDS, then normalize + write ctx ----
    __syncthreads();
    float* Obuf = (float*)&Ks[0][0][0][0];  // 4*16*OSTR*4 = 17408 B
    float* Mbuf = (float*)&Vt[0][0][0][0];  // 128 floats

    if (half == 1) {
        float* ob = Obuf + (size_t)w4 * (16 * OSTR) + (size_t)lrow * OSTR;
        #pragma unroll
        for (int n = 0; n < 4; ++n)
            *(f32x4*)&ob[n * 16 + quad * 4] = oacc[n];
        if (quad == 0) {
            Mbuf[w4 * 16 + lrow]      = m_prev;
            Mbuf[64 + w4 * 16 + lrow] = l_run;
        }
    }
    __syncthreads();
    if (half == 0) {
        const float m1 = Mbuf[w4 * 16 + lrow];
        const float l1 = Mbuf[64 + w4 * 16 + lrow];
        const float M  = fmaxf(m_prev, m1);
        const float a0 = exp2f(m_prev - M), a1 = exp2f(m1 - M);
        const float inv = 1.f / (l_run * a0 + l1 * a1);
        const float s0 = a0 * inv, s1 = a1 * inv;
        const float* ob = Obuf + (size_t)w4 * (16 * OSTR) + (size_t)lrow * OSTR;

        const int b_ = bh >> 3, h_ = bh & 7;
        const int qg = q0 + w4 * 16 + lrow;
        unsigned short* crow = ctx + ((size_t)(b_ * SEQ + qg)) * DMODEL + h_ * HDIM;
        #pragma unroll
        for (int n = 0; n < 4; ++n) {
            f32x4 o1 = *(const f32x4*)&ob[n * 16 + quad * 4];
            uint2 o;
            o.x = pack2(oacc[n][0] * s0 + o1[0] * s1, oacc[n][1] * s0 + o1[1] * s1);
            o.y = pack2(oacc[n][2] * s0 + o1[2] * s1, oacc[n][3] * s0 + o1[3] * s1);
            *(uint2*)&crow[n * 16 + quad * 4] = o;
        }
    }
}

// ---------------------------------------------------------------------------
// Kernel 3: output projection. A (ctx, bf16) read directly per-lane (disjoint
// rows per wave -> no A-LDS); B double-buffered in LDS, 1 barrier per K-step.
// ---------------------------------------------------------------------------
__global__ __launch_bounds__(256) void out_proj_mfma_kernel(
    const unsigned short* __restrict__ ws, const float* __restrict__ bo,
    float* __restrict__ out)
{
    const unsigned short* ctx = ws + WS_CTX;
    const unsigned short* Wt  = ws + WS_WT + 3 * (size_t)WSIZE;

    __shared__ __align__(16) short Bs[2][64][LSTR];

    const int tid = threadIdx.x;
    const int lane = tid & 63, wave = tid >> 6;
    const int lrow = lane & 15, quad = lane >> 4;
    const int m0 = blockIdx.y * 128, n0 = blockIdx.x * 64;

    const int br = tid >> 2, bc = (tid & 3) * 16;
    const unsigned short* wp0 = Wt + (size_t)(n0 + br) * DMODEL + bc;

    const unsigned short* arow0 = ctx + (size_t)(m0 + wave * 32 + lrow) * DMODEL;
    const unsigned short* arow1 = arow0 + 16 * DMODEL;

    f32x4 acc[2][4];
    #pragma unroll
    for (int i = 0; i < 2; ++i)
        #pragma unroll
        for (int n = 0; n < 4; ++n) acc[i][n] = f32x4{0.f, 0.f, 0.f, 0.f};

    uint4 b0, b1;
#define LOADB(K0) do { const unsigned short* wp = wp0 + (K0); \
        b0 = *(const uint4*)(wp + 0); b1 = *(const uint4*)(wp + 8); } while (0)
#define WRITEB(BUF) do { \
        *(uint4*)&Bs[BUF][br][bc]     = b0; \
        *(uint4*)&Bs[BUF][br][bc + 8] = b1; } while (0)

    LOADB(0);
    WRITEB(0);
    LOADB(64);

    #pragma unroll
    for (int kk = 0; kk < 8; ++kk) {
        const int k0 = kk * 64, cur = kk & 1;
        __syncthreads();
        __builtin_amdgcn_s_setprio(1);
        #pragma unroll
        for (int s = 0; s < 2; ++s) {
            const int cb = k0 + s * 32 + quad * 8;
            bf16x8 af0 = *(const bf16x8*)(arow0 + cb);
            bf16x8 af1 = *(const bf16x8*)(arow1 + cb);
            #pragma unroll
            for (int n = 0; n < 4; ++n) {
                bf16x8 bfv = *(const bf16x8*)&Bs[cur][n * 16 + lrow][s * 32 + quad * 8];
                acc[0][n] = __builtin_amdgcn_mfma_f32_16x16x32_bf16(af0, bfv, acc[0][n], 0, 0, 0);
                acc[1][n] = __builtin_amdgcn_mfma_f32_16x16x32_bf16(af1, bfv, acc[1][n], 0, 0, 0);
            }
        }
        __builtin_amdgcn_s_setprio(0);
        if (kk < 7) WRITEB(cur ^ 1);
        if (kk < 6) LOADB(k0 + 128);
    }
#undef LOADB
#undef WRITEB

    #pragma unroll
    for (int n = 0; n < 4; ++n) {
        const int col = n0 + n * 16 + lrow;
        const float bv_ = bo[col];
        #pragma unroll
        for (int i = 0; i < 2; ++i) {
            #pragma unroll
            for (int r = 0; r < 4; ++r) {
                const int m = m0 + wave * 32 + i * 16 + quad * 4 + r;
                out[(size_t)m * DMODEL + col] = acc[i][n][r] + bv_;
            }
        }
    }
}

// ---------------------------------------------------------------------------
extern "C" void kernel_launch(void* const* d_in, const int* in_sizes, int n_in,
                              void* d_out, int out_size, void* d_ws, size_t ws_size,
                              hipStream_t stream)
{
    const float* qin = (const float*)d_in[0];
    const float* kin = (const float*)d_in[1];
    const float* vin = (const float*)d_in[2];
    const float* Wq  = (const float*)d_in[3];
    const float* bq  = (const float*)d_in[4];
    const float* Wk  = (const float*)d_in[5];
    const float* bk  = (const float*)d_in[6];
    const float* Wv  = (const float*)d_in[7];
    const float* bv  = (const float*)d_in[8];
    const float* Wo  = (const float*)d_in[9];
    const float* bo  = (const float*)d_in[10];

    unsigned short* ws = (unsigned short*)d_ws;
    float* out = (float*)d_out;

    dim3 gw(DMODEL / 32, DMODEL / 32, 4);
    wt_prep_kernel<<<gw, 256, 0, stream>>>(Wq, Wk, Wv, Wo, ws + WS_WT);

    dim3 gp(DMODEL / 128, MTOT / 128, 3);
    qkv_mfma_kernel<<<gp, 256, 0, stream>>>(ws, qin, kin, vin, bq, bk, bv);

    dim3 ga(BATCH * NH, SEQ / 64);
    attn_mfma_kernel<<<ga, 512, 0, stream>>>(ws, ws + WS_CTX);

    dim3 go(DMODEL / 64, MTOT / 128);
    out_proj_mfma_kernel<<<go, 256, 0, stream>>>(ws, bo, out);
}

// Round 4
// 147.651 us; speedup vs baseline: 1.0575x; 1.0575x over previous
//
#include <hip/hip_runtime.h>
#include <math.h>

#define BATCH 2
#define SEQ 2048
#define DMODEL 512
#define NH 8
#define HDIM 64
#define MTOT (BATCH * SEQ)              // 4096
#define QSIZE (BATCH * NH * SEQ * HDIM) // 2097152 elems per tensor
#define WSIZE (DMODEL * DMODEL)         // 262144 elems per weight

typedef __attribute__((ext_vector_type(8))) short bf16x8;
typedef __attribute__((ext_vector_type(4))) float f32x4;

__device__ inline unsigned short f2bf(float f) {
    union { float f; unsigned u; } v; v.f = f;
    unsigned u = v.u;
    u += 0x7fffu + ((u >> 16) & 1u);
    return (unsigned short)(u >> 16);
}
// hardware packed f32->bf16 (RTNE), 1 instr
__device__ inline unsigned pack2(float lo, float hi) {
    unsigned r;
    asm("v_cvt_pk_bf16_f32 %0, %1, %2" : "=v"(r) : "v"(lo), "v"(hi));
    return r;
}

// LDS row stride: 72 elems = 144 B (16B-aligned for ds_read_b128).
#define LSTR 72

// ws layout (bf16 elems):
#define WS_Q   ((size_t)0)
#define WS_K   ((size_t)QSIZE)
#define WS_V   (2 * (size_t)QSIZE)        // [B,H,HD,S] transposed
#define WS_CTX (3 * (size_t)QSIZE)
#define WS_WT  (4 * (size_t)QSIZE)        // 4 transposed weights
#define WS_ABF (4 * (size_t)QSIZE + 4 * (size_t)WSIZE)  // bf16 inputs q,k,v

// Q pre-scale: 1/sqrt(64) * log2(e)  (attn uses exp2 directly)
#define QSCALE 0.1803368801111204f

// ---------------------------------------------------------------------------
// Kernel 0: fused prep. Blocks [0,1024): transpose + bf16-convert the 4
// weight matrices. Blocks [1024,4096): fp32 inputs -> bf16 row-major copy.
// One launch instead of two.
// ---------------------------------------------------------------------------
__global__ __launch_bounds__(256) void prep_kernel(
    const float* __restrict__ Wq, const float* __restrict__ Wk,
    const float* __restrict__ Wv, const float* __restrict__ Wo,
    const float* __restrict__ qin, const float* __restrict__ kin,
    const float* __restrict__ vin, unsigned short* __restrict__ ws)
{
    __shared__ float T[32][33];
    const int bid = blockIdx.x;
    const int tid = threadIdx.x;

    if (bid < 1024) {
        const int z = bid >> 8, rem = bid & 255;
        const float* W = (z == 0) ? Wq : (z == 1) ? Wk : (z == 2) ? Wv : Wo;
        unsigned short* Wt = ws + WS_WT + (size_t)z * WSIZE;
        const int k0 = (rem & 15) * 32, n0 = (rem >> 4) * 32;
        {
            int r = tid >> 3, c = (tid & 7) * 4;
            float4 v = *(const float4*)&W[(size_t)(k0 + r) * DMODEL + n0 + c];
            T[r][c + 0] = v.x; T[r][c + 1] = v.y; T[r][c + 2] = v.z; T[r][c + 3] = v.w;
        }
        __syncthreads();
        {
            int n = tid >> 3, c = (tid & 7) * 4;
            uint2 o;
            o.x = pack2(T[c + 0][n], T[c + 1][n]);
            o.y = pack2(T[c + 2][n], T[c + 3][n]);
            *(uint2*)&Wt[(size_t)(n0 + n) * DMODEL + k0 + c] = o;
        }
    } else {
        const int idx = bid - 1024;
        const int z = idx >> 10, blk = idx & 1023;
        const float* src = (z == 0) ? qin : (z == 1) ? kin : vin;
        unsigned short* dst = ws + WS_ABF + (size_t)z * QSIZE;
        const size_t i = ((size_t)blk * 256 + tid) * 8;
        float4 f0 = *(const float4*)(src + i);
        float4 f1 = *(const float4*)(src + i + 4);
        uint4 o;
        o.x = pack2(f0.x, f0.y); o.y = pack2(f0.z, f0.w);
        o.z = pack2(f1.x, f1.y); o.w = pack2(f1.z, f1.w);
        *(uint4*)(dst + i) = o;
    }
}

// ---------------------------------------------------------------------------
// Kernel 1: fused QKV projection, bf16 MFMA, 128x128 tiles, bf16 A from ws.
// LDS-staged A and B (single buffer, 2 barriers/k-step) with T14 reg-prefetch:
// global loads for step k+1 are issued right after the second barrier, hiding
// under step k's 32 MFMAs. Q scaled by QSCALE. Q,K [B,H,S,HD]; V [B,H,HD,S].
// ---------------------------------------------------------------------------
__global__ __launch_bounds__(256) void qkv_mfma_kernel(
    unsigned short* __restrict__ ws,
    const float* __restrict__ bq, const float* __restrict__ bk,
    const float* __restrict__ bv)
{
    const int which = blockIdx.z;
    const unsigned short* A  = ws + WS_ABF + (size_t)which * QSIZE;
    const unsigned short* Wt = ws + WS_WT + (size_t)which * WSIZE;
    const float* bias = (which == 0) ? bq : (which == 1) ? bk : bv;
    unsigned short* out = ws + (size_t)which * QSIZE;

    __shared__ __align__(16) short As[128][LSTR];
    __shared__ __align__(16) short Bs[128][LSTR];

    const int tid = threadIdx.x;
    const int lane = tid & 63, wave = tid >> 6;
    const int lrow = lane & 15, quad = lane >> 4;
    const int m0 = blockIdx.y * 128, n0 = blockIdx.x * 128;

    const int sr = tid >> 1;             // staging row 0..127
    const int sh = (tid & 1) * 32;       // col half (elems)
    const unsigned short* ap0 = A  + (size_t)(m0 + sr) * DMODEL + sh;
    const unsigned short* wp0 = Wt + (size_t)(n0 + sr) * DMODEL + sh;

    f32x4 acc[2][8];
    #pragma unroll
    for (int i = 0; i < 2; ++i)
        #pragma unroll
        for (int n = 0; n < 8; ++n) acc[i][n] = f32x4{0.f, 0.f, 0.f, 0.f};

    uint4 a0, a1, a2, a3, b0, b1, b2, b3;
#define LOADS(K0) do { \
        const unsigned short* ap = ap0 + (K0); \
        const unsigned short* wp = wp0 + (K0); \
        a0 = *(const uint4*)(ap + 0);  a1 = *(const uint4*)(ap + 8); \
        a2 = *(const uint4*)(ap + 16); a3 = *(const uint4*)(ap + 24); \
        b0 = *(const uint4*)(wp + 0);  b1 = *(const uint4*)(wp + 8); \
        b2 = *(const uint4*)(wp + 16); b3 = *(const uint4*)(wp + 24); } while (0)
#define WRITES() do { \
        *(uint4*)&As[sr][sh + 0]  = a0; *(uint4*)&As[sr][sh + 8]  = a1; \
        *(uint4*)&As[sr][sh + 16] = a2; *(uint4*)&As[sr][sh + 24] = a3; \
        *(uint4*)&Bs[sr][sh + 0]  = b0; *(uint4*)&Bs[sr][sh + 8]  = b1; \
        *(uint4*)&Bs[sr][sh + 16] = b2; *(uint4*)&Bs[sr][sh + 24] = b3; } while (0)

    LOADS(0);

    #pragma unroll
    for (int kk = 0; kk < 8; ++kk) {
        const int k0 = kk * 64;
        __syncthreads();               // all waves done reading previous tile
        WRITES();
        __syncthreads();               // tile kk ready
        if (kk < 7) LOADS(k0 + 64);    // issue next-step loads; hide under MFMA
        __builtin_amdgcn_s_setprio(1);
        #pragma unroll
        for (int s = 0; s < 2; ++s) {
            bf16x8 af[2];
            #pragma unroll
            for (int i = 0; i < 2; ++i)
                af[i] = *(const bf16x8*)&As[wave * 32 + i * 16 + lrow][s * 32 + quad * 8];
            #pragma unroll
            for (int n = 0; n < 8; ++n) {
                bf16x8 bfv = *(const bf16x8*)&Bs[n * 16 + lrow][s * 32 + quad * 8];
                acc[0][n] = __builtin_amdgcn_mfma_f32_16x16x32_bf16(af[0], bfv, acc[0][n], 0, 0, 0);
                acc[1][n] = __builtin_amdgcn_mfma_f32_16x16x32_bf16(af[1], bfv, acc[1][n], 0, 0, 0);
            }
        }
        __builtin_amdgcn_s_setprio(0);
    }
#undef LOADS
#undef WRITES

    if (which < 2) {
        const float scale = (which == 0) ? QSCALE : 1.0f;
        #pragma unroll
        for (int n = 0; n < 8; ++n) {
            const int col = n0 + n * 16 + lrow;
            const int h_ = col >> 6, hd_ = col & 63;
            const float bv_ = bias[col];
            #pragma unroll
            for (int i = 0; i < 2; ++i) {
                #pragma unroll
                for (int r = 0; r < 4; ++r) {
                    const int m = m0 + wave * 32 + i * 16 + quad * 4 + r;
                    const int b_ = m >> 11, s_ = m & (SEQ - 1);
                    const float v = (acc[i][n][r] + bv_) * scale;
                    out[((size_t)((b_ * NH + h_) * SEQ + s_)) * HDIM + hd_] = f2bf(v);
                }
            }
        }
    } else {
        #pragma unroll
        for (int n = 0; n < 8; ++n) {
            const int col = n0 + n * 16 + lrow;
            const int h_ = col >> 6, hd_ = col & 63;
            const float bv_ = bias[col];
            #pragma unroll
            for (int i = 0; i < 2; ++i) {
                const int m = m0 + wave * 32 + i * 16 + quad * 4;
                const int b_ = m >> 11, s_ = m & (SEQ - 1);
                uint2 o;
                o.x = pack2(acc[i][n][0] + bv_, acc[i][n][1] + bv_);
                o.y = pack2(acc[i][n][2] + bv_, acc[i][n][3] + bv_);
                *(uint2*)&out[((size_t)((b_ * NH + h_) * HDIM + hd_)) * SEQ + s_] = o;
            }
        }
    }
}

// ---------------------------------------------------------------------------
// Kernel 2: bf16 MFMA flash attention (S^T form, key-split halves,
// double-buffered K/V, zero-shuffle P via tau-permuted Vt columns,
// XCD swizzle, exp2 path, tree max, deferred cross-lane l-reduction).
// grid = (16, 32) swizzled, 512 thr.
// ---------------------------------------------------------------------------
#define HSEQ (SEQ / 2)   // 1024 keys per half
#define NT   (HSEQ / 64) // 16 tiles per half
#define OSTR 68          // merge O buffer row stride (floats), bank-spread
#define THR2 11.0f       // defer-max threshold in log2 units (~e^7.6)

__global__ __launch_bounds__(512) void attn_mfma_kernel(
    const unsigned short* __restrict__ ws, unsigned short* __restrict__ ctx)
{
    const unsigned short* Q = ws + WS_Q;   // pre-scaled by 0.125*log2e
    const unsigned short* K = ws + WS_K;
    const unsigned short* V = ws + WS_V;   // [B,H,HD,S]

    __shared__ __align__(16) short Ks[2][2][64][LSTR];  // [half][buf][key][hd]
    __shared__ __align__(16) short Vt[2][2][64][LSTR];  // [half][buf][hd][perm key]

    // XCD-aware swizzle: bid mod 8 == bh mod 8.
    const int lin = blockIdx.x + 16 * blockIdx.y;          // 0..511
    const int bh  = (lin & 7) + 8 * (lin >> 8);
    const int q0  = ((lin >> 3) & 31) * 64;

    const int tid = threadIdx.x;
    const int lane = tid & 63, wave = tid >> 6;
    const int half = wave >> 2, w4 = wave & 3;
    const int lrow = lane & 15, quad = lane >> 4;
    const size_t base = (size_t)bh * SEQ * HDIM;

    const unsigned short* qrow = Q + base + (size_t)(q0 + w4 * 16 + lrow) * HDIM;
    const bf16x8 qb0 = *(const bf16x8*)(qrow + quad * 8);
    const bf16x8 qb1 = *(const bf16x8*)(qrow + 32 + quad * 8);

    float m_prev = -1e30f, l_run = 0.f;   // m in log2 units; l per-lane partial
    f32x4 oacc[4];
    #pragma unroll
    for (int n = 0; n < 4; ++n) oacc[n] = f32x4{0.f, 0.f, 0.f, 0.f};

    const int t  = tid & 255;
    const int kr = t >> 2;
    const int kc = (t & 3) * 16;
    const int n_ = t & 3;
    const int c0 = ((n_ >= 2) ? 32 : 0) + (n_ & 1) * 4;  // tau col base
    const int ktbase = half * HSEQ;

    const unsigned short* kptr = K + base + (size_t)(ktbase + kr) * HDIM + kc;
    const unsigned short* vptr = V + base + (size_t)kr * SEQ + ktbase + kc;

    uint4 kA, kB, vA, vB;
#define LOADT(TI) do { \
        const unsigned short* kp = kptr + (size_t)(TI) * 64 * HDIM; \
        const unsigned short* vp = vptr + (TI) * 64; \
        kA = *(const uint4*)kp; kB = *(const uint4*)(kp + 8); \
        vA = *(const uint4*)vp; vB = *(const uint4*)(vp + 8); \
    } while (0)
#define WRITET(BUF) do { \
        *(uint4*)&Ks[half][BUF][kr][kc]     = kA; \
        *(uint4*)&Ks[half][BUF][kr][kc + 8] = kB; \
        uint2 w0; w0.x = vA.x; w0.y = vA.y; \
        uint2 w1; w1.x = vA.z; w1.y = vA.w; \
        uint2 w2; w2.x = vB.x; w2.y = vB.y; \
        uint2 w3; w3.x = vB.z; w3.y = vB.w; \
        *(uint2*)&Vt[half][BUF][kr][c0]      = w0; \
        *(uint2*)&Vt[half][BUF][kr][c0 + 8]  = w1; \
        *(uint2*)&Vt[half][BUF][kr][c0 + 16] = w2; \
        *(uint2*)&Vt[half][BUF][kr][c0 + 24] = w3; \
    } while (0)

    LOADT(0);
    WRITET(0);
    LOADT(1);

    #pragma unroll 2
    for (int ti = 0; ti < NT; ++ti) {
        const int cur = ti & 1;
        __syncthreads();

        // ---- S^T = K·Q^T ----
        f32x4 st[4];
        __builtin_amdgcn_s_setprio(1);
        #pragma unroll
        for (int n = 0; n < 4; ++n) {
            bf16x8 ka0 = *(const bf16x8*)&Ks[half][cur][n * 16 + lrow][quad * 8];
            bf16x8 ka1 = *(const bf16x8*)&Ks[half][cur][n * 16 + lrow][32 + quad * 8];
            f32x4 z = f32x4{0.f, 0.f, 0.f, 0.f};
            z = __builtin_amdgcn_mfma_f32_16x16x32_bf16(ka0, qb0, z, 0, 0, 0);
            z = __builtin_amdgcn_mfma_f32_16x16x32_bf16(ka1, qb1, z, 0, 0, 0);
            st[n] = z;
        }
        __builtin_amdgcn_s_setprio(0);

        // ---- max: tree (max3-fusable), then cross-quad shfl ----
        float t0 = fmaxf(fmaxf(st[0][0], st[0][1]), fmaxf(st[0][2], st[0][3]));
        float t1 = fmaxf(fmaxf(st[1][0], st[1][1]), fmaxf(st[1][2], st[1][3]));
        float t2 = fmaxf(fmaxf(st[2][0], st[2][1]), fmaxf(st[2][2], st[2][3]));
        float t3 = fmaxf(fmaxf(st[3][0], st[3][1]), fmaxf(st[3][2], st[3][3]));
        float tmax = fmaxf(fmaxf(t0, t1), fmaxf(t2, t3));
        tmax = fmaxf(tmax, __shfl_xor(tmax, 16));
        tmax = fmaxf(tmax, __shfl_xor(tmax, 32));

        // defer-max (T13): rescale only when max grows past THR2 (log2 units)
        if (!__all(tmax <= m_prev + THR2)) {
            const float mnew = fmaxf(m_prev, tmax);
            const float alpha = exp2f(m_prev - mnew);
            l_run *= alpha;
            #pragma unroll
            for (int n = 0; n < 4; ++n) {
                oacc[n][0] *= alpha; oacc[n][1] *= alpha;
                oacc[n][2] *= alpha; oacc[n][3] *= alpha;
            }
            m_prev = mnew;
        }

        float p[4][4];
        float tsum = 0.f;
        #pragma unroll
        for (int n = 0; n < 4; ++n)
            #pragma unroll
            for (int r = 0; r < 4; ++r) {
                p[n][r] = exp2f(st[n][r] - m_prev);
                tsum += p[n][r];
            }
        l_run += tsum;   // per-lane partial; cross-lane reduce deferred to end

        // ---- P -> PV B-fragments, in-register (zero-shuffle via tau) ----
        union { unsigned w[4]; bf16x8 v; } U0, U1;
        U0.w[0] = pack2(p[0][0], p[0][1]); U0.w[1] = pack2(p[0][2], p[0][3]);
        U0.w[2] = pack2(p[1][0], p[1][1]); U0.w[3] = pack2(p[1][2], p[1][3]);
        U1.w[0] = pack2(p[2][0], p[2][1]); U1.w[1] = pack2(p[2][2], p[2][3]);
        U1.w[2] = pack2(p[3][0], p[3][1]); U1.w[3] = pack2(p[3][2], p[3][3]);

        // ---- O^T += V^T·P^T ----
        __builtin_amdgcn_s_setprio(1);
        #pragma unroll
        for (int n = 0; n < 4; ++n) {
            bf16x8 va0 = *(const bf16x8*)&Vt[half][cur][n * 16 + lrow][quad * 8];
            bf16x8 va1 = *(const bf16x8*)&Vt[half][cur][n * 16 + lrow][32 + quad * 8];
            oacc[n] = __builtin_amdgcn_mfma_f32_16x16x32_bf16(va0, U0.v, oacc[n], 0, 0, 0);
            oacc[n] = __builtin_amdgcn_mfma_f32_16x16x32_bf16(va1, U1.v, oacc[n], 0, 0, 0);
        }
        __builtin_amdgcn_s_setprio(0);

        if (ti < NT - 1) WRITET(cur ^ 1);
        if (ti < NT - 2) LOADT(ti + 2);
    }
#undef LOADT
#undef WRITET

    // deferred l reduction: make l uniform across the 4 lanes sharing a q
    l_run += __shfl_xor(l_run, 16);
    l_run += __shfl_xor(l_run, 32);

    // ---- merge halves through LDS, then normalize + write ctx ----
    __syncthreads();
    float* Obuf = (float*)&Ks[0][0][0][0];  // 4*16*OSTR*4 = 17408 B
    float* Mbuf = (float*)&Vt[0][0][0][0];  // 128 floats

    if (half == 1) {
        float* ob = Obuf + (size_t)w4 * (16 * OSTR) + (size_t)lrow * OSTR;
        #pragma unroll
        for (int n = 0; n < 4; ++n)
            *(f32x4*)&ob[n * 16 + quad * 4] = oacc[n];
        if (quad == 0) {
            Mbuf[w4 * 16 + lrow]      = m_prev;
            Mbuf[64 + w4 * 16 + lrow] = l_run;
        }
    }
    __syncthreads();
    if (half == 0) {
        const float m1 = Mbuf[w4 * 16 + lrow];
        const float l1 = Mbuf[64 + w4 * 16 + lrow];
        const float M  = fmaxf(m_prev, m1);
        const float a0 = exp2f(m_prev - M), a1 = exp2f(m1 - M);
        const float inv = 1.f / (l_run * a0 + l1 * a1);
        const float s0 = a0 * inv, s1 = a1 * inv;
        const float* ob = Obuf + (size_t)w4 * (16 * OSTR) + (size_t)lrow * OSTR;

        const int b_ = bh >> 3, h_ = bh & 7;
        const int qg = q0 + w4 * 16 + lrow;
        unsigned short* crow = ctx + ((size_t)(b_ * SEQ + qg)) * DMODEL + h_ * HDIM;
        #pragma unroll
        for (int n = 0; n < 4; ++n) {
            f32x4 o1 = *(const f32x4*)&ob[n * 16 + quad * 4];
            uint2 o;
            o.x = pack2(oacc[n][0] * s0 + o1[0] * s1, oacc[n][1] * s0 + o1[1] * s1);
            o.y = pack2(oacc[n][2] * s0 + o1[2] * s1, oacc[n][3] * s0 + o1[3] * s1);
            *(uint2*)&crow[n * 16 + quad * 4] = o;
        }
    }
}

// ---------------------------------------------------------------------------
// Kernel 3: output projection, bf16 MFMA, 128x64 tiles. LDS-staged A and B
// (single buffer, 2 barriers/k-step) with T14 reg-prefetch as in qkv.
// ---------------------------------------------------------------------------
__global__ __launch_bounds__(256) void out_proj_mfma_kernel(
    const unsigned short* __restrict__ ws, const float* __restrict__ bo,
    float* __restrict__ out)
{
    const unsigned short* ctx = ws + WS_CTX;
    const unsigned short* Wt  = ws + WS_WT + 3 * (size_t)WSIZE;

    __shared__ __align__(16) short As[128][LSTR];
    __shared__ __align__(16) short Bs[64][LSTR];

    const int tid = threadIdx.x;
    const int lane = tid & 63, wave = tid >> 6;
    const int lrow = lane & 15, quad = lane >> 4;
    const int m0 = blockIdx.y * 128, n0 = blockIdx.x * 64;

    const int sr = tid >> 1, sh = (tid & 1) * 32;
    const int br = tid >> 2, bqr = (tid & 3) * 16;
    const unsigned short* ap0 = ctx + (size_t)(m0 + sr) * DMODEL + sh;
    const unsigned short* wp0 = Wt + (size_t)(n0 + br) * DMODEL + bqr;

    f32x4 acc[2][4];
    #pragma unroll
    for (int i = 0; i < 2; ++i)
        #pragma unroll
        for (int n = 0; n < 4; ++n) acc[i][n] = f32x4{0.f, 0.f, 0.f, 0.f};

    uint4 a0, a1, a2, a3, b0, b1;
#define LOADS(K0) do { \
        const unsigned short* ap = ap0 + (K0); \
        const unsigned short* wp = wp0 + (K0); \
        a0 = *(const uint4*)(ap + 0);  a1 = *(const uint4*)(ap + 8); \
        a2 = *(const uint4*)(ap + 16); a3 = *(const uint4*)(ap + 24); \
        b0 = *(const uint4*)wp; b1 = *(const uint4*)(wp + 8); } while (0)
#define WRITES() do { \
        *(uint4*)&As[sr][sh + 0]  = a0; *(uint4*)&As[sr][sh + 8]  = a1; \
        *(uint4*)&As[sr][sh + 16] = a2; *(uint4*)&As[sr][sh + 24] = a3; \
        *(uint4*)&Bs[br][bqr]     = b0; *(uint4*)&Bs[br][bqr + 8] = b1; } while (0)

    LOADS(0);

    #pragma unroll
    for (int kk = 0; kk < 8; ++kk) {
        const int k0 = kk * 64;
        __syncthreads();
        WRITES();
        __syncthreads();
        if (kk < 7) LOADS(k0 + 64);
        __builtin_amdgcn_s_setprio(1);
        #pragma unroll
        for (int s = 0; s < 2; ++s) {
            bf16x8 af[2];
            #pragma unroll
            for (int i = 0; i < 2; ++i)
                af[i] = *(const bf16x8*)&As[wave * 32 + i * 16 + lrow][s * 32 + quad * 8];
            #pragma unroll
            for (int n = 0; n < 4; ++n) {
                bf16x8 bfv = *(const bf16x8*)&Bs[n * 16 + lrow][s * 32 + quad * 8];
                acc[0][n] = __builtin_amdgcn_mfma_f32_16x16x32_bf16(af[0], bfv, acc[0][n], 0, 0, 0);
                acc[1][n] = __builtin_amdgcn_mfma_f32_16x16x32_bf16(af[1], bfv, acc[1][n], 0, 0, 0);
            }
        }
        __builtin_amdgcn_s_setprio(0);
    }
#undef LOADS
#undef WRITES

    #pragma unroll
    for (int n = 0; n < 4; ++n) {
        const int col = n0 + n * 16 + lrow;
        const float bv_ = bo[col];
        #pragma unroll
        for (int i = 0; i < 2; ++i) {
            #pragma unroll
            for (int r = 0; r < 4; ++r) {
                const int m = m0 + wave * 32 + i * 16 + quad * 4 + r;
                out[(size_t)m * DMODEL + col] = acc[i][n][r] + bv_;
            }
        }
    }
}

// ---------------------------------------------------------------------------
extern "C" void kernel_launch(void* const* d_in, const int* in_sizes, int n_in,
                              void* d_out, int out_size, void* d_ws, size_t ws_size,
                              hipStream_t stream)
{
    const float* qin = (const float*)d_in[0];
    const float* kin = (const float*)d_in[1];
    const float* vin = (const float*)d_in[2];
    const float* Wq  = (const float*)d_in[3];
    const float* bq  = (const float*)d_in[4];
    const float* Wk  = (const float*)d_in[5];
    const float* bk  = (const float*)d_in[6];
    const float* Wv  = (const float*)d_in[7];
    const float* bv  = (const float*)d_in[8];
    const float* Wo  = (const float*)d_in[9];
    const float* bo  = (const float*)d_in[10];

    unsigned short* ws = (unsigned short*)d_ws;
    float* out = (float*)d_out;

    prep_kernel<<<4096, 256, 0, stream>>>(Wq, Wk, Wv, Wo, qin, kin, vin, ws);

    dim3 gp(DMODEL / 128, MTOT / 128, 3);
    qkv_mfma_kernel<<<gp, 256, 0, stream>>>(ws, bq, bk, bv);

    dim3 ga(BATCH * NH, SEQ / 64);
    attn_mfma_kernel<<<ga, 512, 0, stream>>>(ws, ws + WS_CTX);

    dim3 go(DMODEL / 64, MTOT / 128);
    out_proj_mfma_kernel<<<go, 256, 0, stream>>>(ws, bo, out);
}